// Round 18
// baseline (56.577 us; speedup 1.0000x reference)
//
#include <hip/hip_runtime.h>
#include <math.h>

constexpr int B = 4, C = 64, H = 80, W = 80;
constexpr int HW = H * W;            // 6400
constexpr int NPIX = B * HW;         // 25600
constexpr int PXB = 16;              // pixels per block (16 | W=80)
constexpr int NTILE1 = NPIX / PXB;   // 1600 stage1 blocks (plain launch —
                                     // R13-R16: every alternative regressed)
constexpr int NTILE2 = NPIX / 64;    // 400 m2cv3 blocks

typedef unsigned u32;
typedef float f32x2 __attribute__((ext_vector_type(2)));

static __device__ __forceinline__ float silu(float v) {
    float e = __expf(-v);
    return v * __builtin_amdgcn_rcpf(1.0f + e);
}

// ---- packed u16 helpers (both GLCM channels in one instruction) -----------
static __device__ __forceinline__ u32 pks(u32 a, u32 b){u32 d; asm("v_pk_sub_u16 %0,%1,%2":"=v"(d):"v"(a),"v"(b)); return d;}
static __device__ __forceinline__ u32 pka(u32 a, u32 b){u32 d; asm("v_pk_add_u16 %0,%1,%2":"=v"(d):"v"(a),"v"(b)); return d;}
static __device__ __forceinline__ u32 pkm(u32 a, u32 b){u32 d; asm("v_pk_mul_lo_u16 %0,%1,%2":"=v"(d):"v"(a),"v"(b)); return d;}
static __device__ __forceinline__ u32 pkmin(u32 a, u32 b){u32 d; asm("v_pk_min_u16 %0,%1,%2":"=v"(d):"v"(a),"v"(b)); return d;}
static __device__ __forceinline__ u32 pkmaxi(u32 a, u32 b){u32 d; asm("v_pk_max_i16 %0,%1,%2":"=v"(d):"v"(a),"v"(b)); return d;}
static __device__ __forceinline__ float cb0(u32 a){float f; asm("v_cvt_f32_ubyte0 %0,%1":"=v"(f):"v"(a)); return f;}
static __device__ __forceinline__ float cb2(u32 a){float f; asm("v_cvt_f32_ubyte2 %0,%1":"=v"(f):"v"(a)); return f;}

// byte shuffle/LUT and byte-sum
static __device__ __forceinline__ u32 permb(u32 hi, u32 lo, u32 sel){
    u32 d; asm("v_perm_b32 %0, %1, %2, %3" : "=v"(d) : "v"(hi), "v"(lo), "v"(sel)); return d;}
static __device__ __forceinline__ u32 sad8(u32 a, u32 b, u32 c){
    u32 d; asm("v_sad_u8 %0, %1, %2, %3" : "=v"(d) : "v"(a), "v"(b), "v"(c)); return d;}

// packed compare-exchange: both u16 halves sorted independently (2 channels)
static __device__ __forceinline__ void ce(u32 &x, u32 &y) {
    u32 mn, mx;
    asm("v_pk_min_u16 %0, %2, %3\n\t"
        "v_pk_max_u16 %1, %2, %3"
        : "=&v"(mn), "=v"(mx) : "v"(x), "v"(y));
    x = mn; y = mx;
}

// ---------------------------------------------------------------------------
// Kernel 1: GLCM + cv1 + cv2 + m1 fused. block 512 = 16 px x 32 ch-pairs.
// R18 change (single): phase-2 conv remapped to (2px, 1oc) per thread —
// 256 threads x 68 b128 reads replaces 512 x 51 (−33% LDS-read issues at
// identical FLOPs; A3 was ~2.7 FMA/read, LDS-pipe co-critical with VALU).
// px pair = (p, p+8) so deferred stores stay coalesced (t=0..7 -> px 0..7).
// Everything else identical to the 56.0-µs R17 build.
// ---------------------------------------------------------------------------
__global__ __launch_bounds__(512, 4) void glcm_stage1_kernel(
    const float* __restrict__ x,
    const float* __restrict__ w1, const float* __restrict__ s1, const float* __restrict__ b1,
    const float* __restrict__ w2, const float* __restrict__ s2, const float* __restrict__ b2,
    const float* __restrict__ wm1, const float* __restrict__ sm1, const float* __restrict__ bm1,
    float* __restrict__ a, float* __restrict__ bbuf, float* __restrict__ y16) {
    __shared__ u32 qcell[32][3][18];              // packed quantized stencil rows
    __shared__ __align__(16) float xs[PXB][76];   // [px][68 ic + 4 g], pad 76
    __shared__ __align__(16) float ws1[32][68];   // cv1 weights, natural layout
    __shared__ __align__(16) float ws2[32][68];
    __shared__ __align__(16) float wsm1[16][32];
    __shared__ __align__(16) float aT[PXB][34];   // cv1 out tile (b64-aligned)
    __shared__ float red[8][PXB][4];

    const int t = threadIdx.x;
    const int p0g = blockIdx.x * PXB;
    const int bb  = p0g / HW;
    const int hw0 = p0g - bb * HW;
    const int h0  = hw0 / W;
    const int c0g = hw0 - h0 * W;        // col base (block is 16 px in one row)

    // ---- phase 0a: weights -> LDS (float4 linear copies) ----
    {
        const float4* w1f = (const float4*)w1;
        const float4* w2f = (const float4*)w2;
        float4* s1f = (float4*)&ws1[0][0];
        float4* s2f = (float4*)&ws2[0][0];
        for (int e = t; e < 544; e += 512) { s1f[e] = w1f[e]; s2f[e] = w2f[e]; }
        if (t < 128) ((float4*)&wsm1[0][0])[t] = ((const float4*)wm1)[t];
    }
    // ---- phase 0b: quantize stencil rows once, pack both channels ----
    for (int e = t; e < 32 * 3 * 18; e += 512) {
        const int grp = e / 54;
        const int rem = e - grp * 54;
        const int row = rem / 18;        // 0..2  (image rows h0-1..h0+1, clamped)
        const int col = rem - row * 18;  // 0..17 (image cols c0g-1..c0g+16, clamped)
        int gr = h0 + row - 1;  gr = gr < 0 ? 0 : (gr > H - 1 ? H - 1 : gr);
        int gc = c0g + col - 1; gc = gc < 0 ? 0 : (gc > W - 1 ? W - 1 : gc);
        const float v0 = x[((size_t)(bb * C + grp * 2)) * HW + gr * W + gc];
        const float v1 = x[((size_t)(bb * C + grp * 2 + 1)) * HW + gr * W + gc];
        int q0 = (int)(v0 * 7.0f); q0 = q0 < 0 ? 0 : (q0 > 7 ? 7 : q0);
        int q1 = (int)(v1 * 7.0f); q1 = q1 < 0 ? 0 : (q1 > 7 ? 7 : q1);
        qcell[grp][row][col] = (u32)q0 | ((u32)q1 << 16);
        if (row == 1 && col >= 1 && col <= 16) {   // raw centers for the convs
            xs[col - 1][grp * 2]     = v0;
            xs[col - 1][grp * 2 + 1] = v1;
        }
    }
    __syncthreads();

    // ---- phase 1: GLCM (packed-u16 core; 9 LDS reads, zero quantize) ----
    const int pxl = t & 15;              // 0..15
    const int grp = t >> 4;              // 0..31 (channel pair)
    u32 qpk[9];
    #pragma unroll
    for (int r = 0; r < 3; ++r)
        #pragma unroll
        for (int k = 0; k < 3; ++k)
            qpk[r * 3 + k] = qcell[grp][r][pxl + k];

    static constexpr int PA[20] = {0,1,3,4,6,7, 0,1,2,3,4,5, 0,1,3,4, 1,2,4,5};
    static constexpr int PB[20] = {1,2,4,5,7,8, 3,4,5,6,7,8, 4,5,7,8, 3,4,6,7};

    const u32 ONEpk = 0x00010001u, EIGHTpk = 0x00080008u;
    u32 key[20];
    u32 csI = 0, hloI = 0, hhiI = 0;     // integer byte-sums (both channels)
    const u32 z0 = 0;
    #pragma unroll
    for (int j = 0; j < 10; ++j) {
        u32 adp0, adp1;
        {
            const u32 qa = qpk[PA[2*j]], qb = qpk[PB[2*j]];
            const u32 d = pks(qa, qb);
            adp0 = pkmaxi(d, pks(0u, d));              // |d| per half, 0..7
            key[2*j] = pka(pkm(qa, EIGHTpk), qb);      // qa*8+qb per half
        }
        {
            const u32 qa = qpk[PA[2*j+1]], qb = qpk[PB[2*j+1]];
            const u32 d = pks(qa, qb);
            adp1 = pkmaxi(d, pks(0u, d));
            key[2*j+1] = pka(pkm(qa, EIGHTpk), qb);
        }
        // pack 4 |d| bytes: {adp0.ch0, adp0.ch1, adp1.ch0, adp1.ch1}
        const u32 pk4 = permb(adp1, adp0, 0x06040200u);
        // d^2 LUT {0,1,4,9 | 16,25,36,49}; byte-sum via sad
        csI  = sad8(permb(0x31241910u, 0x09040100u, pk4), z0, csI);
        // 840/(1+|d|) = {840,420,280,210,168,140,120,105}: lo/hi byte LUTs
        hloI = sad8(permb(0x69788CA8u, 0xD218A448u, pk4), z0, hloI);
        hhiI = sad8(permb(0x00000000u, 0x00010103u, pk4), z0, hhiI);
    }

    // Batcher odd-even mergesort for n=32, pruned to the low 20 slots
    #pragma unroll
    for (int p = 1; p < 32; p <<= 1) {
        #pragma unroll
        for (int k = p; k >= 1; k >>= 1) {
            const int jm = k % p;
            #pragma unroll
            for (int lo = 0; lo < 20; ++lo) {
                const int hi = lo + k;
                if (hi < 20 && lo >= jm && ((lo - jm) % (2 * k)) < k &&
                    (lo / (2 * p)) == (hi / (2 * p))) {
                    ce(key[lo], key[hi]);
                }
            }
        }
    }

    // boundary flags: eq[a] = (key[a]==key[a-1]) per half as 0/1 (packed)
    u32 eq[20];
    #pragma unroll
    for (int ai = 1; ai < 20; ++ai)
        eq[ai] = pks(ONEpk, pkmin(pks(key[ai], key[ai - 1]), ONEpk));

    // forward run scan: pc = (pc+1)*eq  (packed), psum += pc
    u32 pc = 0, ps = 0, pv[20];
    pv[0] = 0;
    #pragma unroll
    for (int ai = 1; ai < 20; ++ai) {
        pc = pkm(pka(pc, ONEpk), eq[ai]);
        pv[ai] = pc;
        ps = pka(ps, pc);
    }
    // backward run scan + multiplicity product: m = p + r + 1 (<=20, byte)
    float pr0, pr1;
    {
        const u32 m = pka(pv[19], ONEpk);
        pr0 = cb0(m); pr1 = cb2(m);
    }
    u32 rc = 0;
    #pragma unroll
    for (int ai = 18; ai >= 0; --ai) {
        rc = pkm(pka(rc, ONEpk), eq[ai + 1]);
        const u32 m = pka(pka(pv[ai], rc), ONEpk);
        pr0 *= cb0(m); pr1 *= cb2(m);
    }

    const int psum = (int)(ps & 0xFFFFu) + (int)(ps >> 16);
    const float lsum = __logf(pr0) + __logf(pr1);

    float fc = (float)csI * (1.f / 20.f);                // contrast (both ch)
    float fe = ((float)psum * 2.f + 40.f) * (1.f / 400.f);
    float fn = -(lsum + 40.f * -2.9957322736f) * (1.f / 20.f);
    float fh = (float)(hloI + (hhiI << 8)) * (1.f / 16800.f);  // /840/20

    // reduce over 4 ch-pairs within the wave (lane bits 4,5), then 8 waves
    fc += __shfl_xor(fc, 16); fe += __shfl_xor(fe, 16);
    fn += __shfl_xor(fn, 16); fh += __shfl_xor(fh, 16);
    fc += __shfl_xor(fc, 32); fe += __shfl_xor(fe, 32);
    fn += __shfl_xor(fn, 32); fh += __shfl_xor(fh, 32);
    const int wv = t >> 6;               // 0..7
    if ((t & 63) < 16) {
        red[wv][pxl][0] = fc; red[wv][pxl][1] = fe;
        red[wv][pxl][2] = fn; red[wv][pxl][3] = fh;
    }
    __syncthreads();
    if (t < 64) {
        const int p2 = t >> 2, f = t & 3;
        float s = 0.f;
        #pragma unroll
        for (int wq = 0; wq < 8; ++wq) s += red[wq][p2][f];
        xs[p2][64 + f] = s * (1.f / 64.f);   // g appended to xs in LDS
    }
    __syncthreads();   // xs (x centers + g) complete

    // ---- phase 2: cv1 + cv2, (2px, 1oc) per thread, 256 threads.
    //      f32x2 accumulation; global stores DEFERRED past the barrier. ----
    const int px0 = t & 7;               // pixels px0 and px0+8
    const int ocx = t >> 3;              // 0..31 for t<256
    float v1a, v2a, v1b, v2b;
    if (t < 256) {
        f32x2 a1l0 = {0.f,0.f}, a1h0 = {0.f,0.f}, a2l0 = {0.f,0.f}, a2h0 = {0.f,0.f};
        f32x2 a1l1 = {0.f,0.f}, a1h1 = {0.f,0.f}, a2l1 = {0.f,0.f}, a2h1 = {0.f,0.f};
        #pragma unroll
        for (int k = 0; k < 17; ++k) {
            const float4 x0 = *reinterpret_cast<const float4*>(&xs[px0][k * 4]);
            const float4 x1 = *reinterpret_cast<const float4*>(&xs[px0 + 8][k * 4]);
            const float4 wa = *reinterpret_cast<const float4*>(&ws1[ocx][k * 4]);
            const float4 wb = *reinterpret_cast<const float4*>(&ws2[ocx][k * 4]);
            const f32x2 wal = {wa.x, wa.y}, wah = {wa.z, wa.w};
            const f32x2 wbl = {wb.x, wb.y}, wbh = {wb.z, wb.w};
            a1l0 += (f32x2){x0.x, x0.y} * wal;
            a1h0 += (f32x2){x0.z, x0.w} * wah;
            a2l0 += (f32x2){x0.x, x0.y} * wbl;
            a2h0 += (f32x2){x0.z, x0.w} * wbh;
            a1l1 += (f32x2){x1.x, x1.y} * wal;
            a1h1 += (f32x2){x1.z, x1.w} * wah;
            a2l1 += (f32x2){x1.x, x1.y} * wbl;
            a2h1 += (f32x2){x1.z, x1.w} * wbh;
        }
        const float sA = s1[ocx], bA = b1[ocx];
        const float sB = s2[ocx], bB = b2[ocx];
        v1a = silu((a1l0.x + a1l0.y + a1h0.x + a1h0.y) * sA + bA);
        v1b = silu((a1l1.x + a1l1.y + a1h1.x + a1h1.y) * sA + bA);
        v2a = silu((a2l0.x + a2l0.y + a2h0.x + a2h0.y) * sB + bB);
        v2b = silu((a2l1.x + a2l1.y + a2h1.x + a2h1.y) * sB + bB);
        aT[px0][ocx]     = v1a;          // LDS only before the barrier
        aT[px0 + 8][ocx] = v1b;
    }
    __syncthreads();                     // drains lgkm only (no global stores)

    // ---- phase 3: m1 (f32x2), thread = (px, oc16), first 256 threads ----
    float ymout = 0.f;
    if (t < 256) {
        const int pxm = t & 15;
        const int oc16 = t >> 4;
        f32x2 A = {0.f, 0.f};
        #pragma unroll
        for (int k = 0; k < 16; ++k) {
            const f32x2 av = *reinterpret_cast<const f32x2*>(&aT[pxm][k * 2]);
            const f32x2 wv2 = *reinterpret_cast<const f32x2*>(&wsm1[oc16][k * 2]);
            A += av * wv2;
        }
        ymout = silu((A.x + A.y) * sm1[oc16] + bm1[oc16]);
    }

    // ---- deferred global stores (drain at kernel end, not at a barrier) ----
    if (t < 256) {
        const size_t rowA = ((size_t)(bb * 32 + ocx)) * HW + hw0;
        a[rowA + px0]        = v1a;
        a[rowA + px0 + 8]    = v1b;
        bbuf[rowA + px0]     = v2a;
        bbuf[rowA + px0 + 8] = v2b;
        y16[((size_t)(bb * 16 + (t >> 4))) * HW + hw0 + (t & 15)] = ymout;
    }
}

// ---------------------------------------------------------------------------
// Kernel 2: m2 (3x3, 16->32, pad 1) + BN + SiLU + residual, then cv3
// (1x1, 64->64). The proven 512-thread 8-wave structure. Frozen.
// ---------------------------------------------------------------------------
__global__ __launch_bounds__(512) void m2cv3_kernel(
    const float* __restrict__ y16, const float* __restrict__ a,
    const float* __restrict__ bbuf,
    const float* __restrict__ wm2, const float* __restrict__ sm2, const float* __restrict__ bm2,
    const float* __restrict__ wc, const float* __restrict__ sc, const float* __restrict__ bc,
    float* __restrict__ out) {
    __shared__ float ys[16][4][82];
    __shared__ float a2[32][64];
    __shared__ float bs[32][64];
    const int t = threadIdx.x;
    const int p0 = blockIdx.x * 64;
    const int bi = p0 / HW;
    const int hw0 = p0 - bi * HW;
    const int h0 = hw0 / W;

    const float* yb = y16 + (size_t)(bi * 16) * HW;
    for (int e = t; e < 16 * 4 * 82; e += 512) {
        const int ch = e / 328;
        const int rem = e - ch * 328;
        const int row = rem / 82;
        const int col = rem - row * 82;
        const int r = h0 - 1 + row;
        const int c = col - 1;
        float v = 0.f;
        if ((unsigned)r < (unsigned)H && (unsigned)c < (unsigned)W)
            v = yb[(size_t)ch * HW + r * W + c];
        ys[ch][row][col] = v;
    }
    for (int e = t; e < 32 * 64; e += 512) {
        const int ic = e >> 6, px = e & 63;
        bs[ic][px] = bbuf[((size_t)(bi * 32 + ic)) * HW + hw0 + px];
    }
    __syncthreads();

    const int lane = t & 63;
    const int wv = __builtin_amdgcn_readfirstlane(t >> 6);
    const int hw = hw0 + lane;
    const int h = hw / W;
    const int w = hw - h * W;
    const int lr = h - h0;
    const int oc0 = wv * 4;

    float acc[4] = {0.f, 0.f, 0.f, 0.f};
    #pragma unroll 2
    for (int ic = 0; ic < 16; ++ic) {
        #pragma unroll
        for (int ky = 0; ky < 3; ++ky) {
            #pragma unroll
            for (int kx = 0; kx < 3; ++kx) {
                const float v = ys[ic][lr + ky][w + kx];
                const int tap = ic * 9 + ky * 3 + kx;
                #pragma unroll
                for (int j = 0; j < 4; ++j)
                    acc[j] += v * wm2[(oc0 + j) * 144 + tap];
            }
        }
    }
    #pragma unroll
    for (int j = 0; j < 4; ++j) {
        const int oc = oc0 + j;
        a2[oc][lane] = a[((size_t)(bi * 32 + oc)) * HW + hw]
                     + silu(acc[j] * sm2[oc] + bm2[oc]);
    }
    __syncthreads();
    const int oc3 = wv * 8;
    float c_[8] = {0.f, 0.f, 0.f, 0.f, 0.f, 0.f, 0.f, 0.f};
    #pragma unroll 4
    for (int ic = 0; ic < 32; ++ic) {
        const float av = a2[ic][lane];
        const float bv = bs[ic][lane];
        #pragma unroll
        for (int j = 0; j < 8; ++j) {
            c_[j] += av * wc[(oc3 + j) * 64 + ic];
            c_[j] += bv * wc[(oc3 + j) * 64 + 32 + ic];
        }
    }
    #pragma unroll
    for (int j = 0; j < 8; ++j) {
        const int oc = oc3 + j;
        out[((size_t)(bi * 64 + oc)) * HW + hw] = silu(c_[j] * sc[oc] + bc[oc]);
    }
}

// ---------------------------------------------------------------------------
extern "C" void kernel_launch(void* const* d_in, const int* in_sizes, int n_in,
                              void* d_out, int out_size, void* d_ws, size_t ws_size,
                              hipStream_t stream) {
    const float* x    = (const float*)d_in[0];
    const float* cv1w = (const float*)d_in[1];
    const float* cv1s = (const float*)d_in[2];
    const float* cv1b = (const float*)d_in[3];
    const float* cv2w = (const float*)d_in[4];
    const float* cv2s = (const float*)d_in[5];
    const float* cv2b = (const float*)d_in[6];
    const float* m1w  = (const float*)d_in[7];
    const float* m1s  = (const float*)d_in[8];
    const float* m1b  = (const float*)d_in[9];
    const float* m2w  = (const float*)d_in[10];
    const float* m2s  = (const float*)d_in[11];
    const float* m2b  = (const float*)d_in[12];
    const float* cv3w = (const float*)d_in[13];
    const float* cv3s = (const float*)d_in[14];
    const float* cv3b = (const float*)d_in[15];

    float* ws   = (float*)d_ws;
    float* a    = ws;                 // 4*32*6400 = 819200
    float* bbuf = ws + 819200;        // 819200
    float* y16  = ws + 1638400;       // 409600 (end 2048000)

    glcm_stage1_kernel<<<NTILE1, 512, 0, stream>>>(
        x, cv1w, cv1s, cv1b, cv2w, cv2s, cv2b, m1w, m1s, m1b, a, bbuf, y16);
    m2cv3_kernel<<<NTILE2, 512, 0, stream>>>(
        y16, a, bbuf, m2w, m2s, m2b, cv3w, cv3s, cv3b, (float*)d_out);
}

// Round 19
// 56.529 us; speedup vs baseline: 1.0009x; 1.0009x over previous
//
#include <hip/hip_runtime.h>
#include <math.h>

constexpr int B = 4, C = 64, H = 80, W = 80;
constexpr int HW = H * W;            // 6400
constexpr int NPIX = B * HW;         // 25600
constexpr int PXB = 16;              // pixels per block (16 | W=80)
constexpr int NTILE1 = NPIX / PXB;   // 1600 stage1 blocks (plain launch —
                                     // R13-R16: every alternative regressed)
constexpr int NTILE2 = NPIX / 64;    // 400 m2cv3 blocks

typedef unsigned u32;
typedef float f32x2 __attribute__((ext_vector_type(2)));

static __device__ __forceinline__ float silu(float v) {
    float e = __expf(-v);
    return v * __builtin_amdgcn_rcpf(1.0f + e);
}

// ---- packed u16 helpers (both GLCM channels in one instruction) -----------
static __device__ __forceinline__ u32 pks(u32 a, u32 b){u32 d; asm("v_pk_sub_u16 %0,%1,%2":"=v"(d):"v"(a),"v"(b)); return d;}
static __device__ __forceinline__ u32 pka(u32 a, u32 b){u32 d; asm("v_pk_add_u16 %0,%1,%2":"=v"(d):"v"(a),"v"(b)); return d;}
static __device__ __forceinline__ u32 pkm(u32 a, u32 b){u32 d; asm("v_pk_mul_lo_u16 %0,%1,%2":"=v"(d):"v"(a),"v"(b)); return d;}
static __device__ __forceinline__ u32 pkmin(u32 a, u32 b){u32 d; asm("v_pk_min_u16 %0,%1,%2":"=v"(d):"v"(a),"v"(b)); return d;}
static __device__ __forceinline__ u32 pkmaxi(u32 a, u32 b){u32 d; asm("v_pk_max_i16 %0,%1,%2":"=v"(d):"v"(a),"v"(b)); return d;}
static __device__ __forceinline__ float cb0(u32 a){float f; asm("v_cvt_f32_ubyte0 %0,%1":"=v"(f):"v"(a)); return f;}
static __device__ __forceinline__ float cb2(u32 a){float f; asm("v_cvt_f32_ubyte2 %0,%1":"=v"(f):"v"(a)); return f;}

// byte shuffle/LUT and byte-sum
static __device__ __forceinline__ u32 permb(u32 hi, u32 lo, u32 sel){
    u32 d; asm("v_perm_b32 %0, %1, %2, %3" : "=v"(d) : "v"(hi), "v"(lo), "v"(sel)); return d;}
static __device__ __forceinline__ u32 sad8(u32 a, u32 b, u32 c){
    u32 d; asm("v_sad_u8 %0, %1, %2, %3" : "=v"(d) : "v"(a), "v"(b), "v"(c)); return d;}

// packed compare-exchange: both u16 halves sorted independently (2 channels)
static __device__ __forceinline__ void ce(u32 &x, u32 &y) {
    u32 mn, mx;
    asm("v_pk_min_u16 %0, %2, %3\n\t"
        "v_pk_max_u16 %1, %2, %3"
        : "=&v"(mn), "=v"(mx) : "v"(x), "v"(y));
    x = mn; y = mx;
}

// ---------------------------------------------------------------------------
// Kernel 1: GLCM + cv1 + cv2 + m1 fused. block 512 = 16 px x 32 ch-pairs.
// Base = R17's 56.0-µs build. R19 changes (two small cuts):
//  (1) cross-wave g-reduction via ds_add_f32 into xs[px][64..67] (zeroed in
//      phase 0a): removes one __syncthreads, the 64-thread reduce pass, and
//      the 2KB red[] array. Wave-internal adds are conflict-free (16 px).
//  (2) one __logf instead of two: log(pr0)+log(pr1) =
//      log((pr0*2^-44)*(pr1*2^-44)) + 88*ln2 (stays in f32 range).
// ---------------------------------------------------------------------------
__global__ __launch_bounds__(512, 4) void glcm_stage1_kernel(
    const float* __restrict__ x,
    const float* __restrict__ w1, const float* __restrict__ s1, const float* __restrict__ b1,
    const float* __restrict__ w2, const float* __restrict__ s2, const float* __restrict__ b2,
    const float* __restrict__ wm1, const float* __restrict__ sm1, const float* __restrict__ bm1,
    float* __restrict__ a, float* __restrict__ bbuf, float* __restrict__ y16) {
    __shared__ u32 qcell[32][3][18];              // packed quantized stencil rows
    __shared__ __align__(16) float xs[PXB][76];   // [px][68 ic + 4 g], pad 76
    __shared__ __align__(16) float ws1[32][68];   // cv1 weights, natural layout
    __shared__ __align__(16) float ws2[32][68];
    __shared__ __align__(16) float wsm1[16][32];
    __shared__ __align__(16) float aT[PXB][34];   // cv1 out tile (b64-aligned)

    const int t = threadIdx.x;
    const int p0g = blockIdx.x * PXB;
    const int bb  = p0g / HW;
    const int hw0 = p0g - bb * HW;
    const int h0  = hw0 / W;
    const int c0g = hw0 - h0 * W;        // col base (block is 16 px in one row)

    // ---- phase 0a: weights -> LDS; zero the g accumulators ----
    {
        const float4* w1f = (const float4*)w1;
        const float4* w2f = (const float4*)w2;
        float4* s1f = (float4*)&ws1[0][0];
        float4* s2f = (float4*)&ws2[0][0];
        for (int e = t; e < 544; e += 512) { s1f[e] = w1f[e]; s2f[e] = w2f[e]; }
        if (t < 128) ((float4*)&wsm1[0][0])[t] = ((const float4*)wm1)[t];
        if (t < 64) xs[t >> 2][64 + (t & 3)] = 0.f;   // g accum zero-init
    }
    // ---- phase 0b: quantize stencil rows once, pack both channels ----
    for (int e = t; e < 32 * 3 * 18; e += 512) {
        const int grp = e / 54;
        const int rem = e - grp * 54;
        const int row = rem / 18;        // 0..2  (image rows h0-1..h0+1, clamped)
        const int col = rem - row * 18;  // 0..17 (image cols c0g-1..c0g+16, clamped)
        int gr = h0 + row - 1;  gr = gr < 0 ? 0 : (gr > H - 1 ? H - 1 : gr);
        int gc = c0g + col - 1; gc = gc < 0 ? 0 : (gc > W - 1 ? W - 1 : gc);
        const float v0 = x[((size_t)(bb * C + grp * 2)) * HW + gr * W + gc];
        const float v1 = x[((size_t)(bb * C + grp * 2 + 1)) * HW + gr * W + gc];
        int q0 = (int)(v0 * 7.0f); q0 = q0 < 0 ? 0 : (q0 > 7 ? 7 : q0);
        int q1 = (int)(v1 * 7.0f); q1 = q1 < 0 ? 0 : (q1 > 7 ? 7 : q1);
        qcell[grp][row][col] = (u32)q0 | ((u32)q1 << 16);
        if (row == 1 && col >= 1 && col <= 16) {   // raw centers for the convs
            xs[col - 1][grp * 2]     = v0;
            xs[col - 1][grp * 2 + 1] = v1;
        }
    }
    __syncthreads();

    // ---- phase 1: GLCM (packed-u16 core; 9 LDS reads, zero quantize) ----
    const int pxl = t & 15;              // 0..15
    const int grp = t >> 4;              // 0..31 (channel pair)
    u32 qpk[9];
    #pragma unroll
    for (int r = 0; r < 3; ++r)
        #pragma unroll
        for (int k = 0; k < 3; ++k)
            qpk[r * 3 + k] = qcell[grp][r][pxl + k];

    static constexpr int PA[20] = {0,1,3,4,6,7, 0,1,2,3,4,5, 0,1,3,4, 1,2,4,5};
    static constexpr int PB[20] = {1,2,4,5,7,8, 3,4,5,6,7,8, 4,5,7,8, 3,4,6,7};

    const u32 ONEpk = 0x00010001u, EIGHTpk = 0x00080008u;
    u32 key[20];
    u32 csI = 0, hloI = 0, hhiI = 0;     // integer byte-sums (both channels)
    const u32 z0 = 0;
    #pragma unroll
    for (int j = 0; j < 10; ++j) {
        u32 adp0, adp1;
        {
            const u32 qa = qpk[PA[2*j]], qb = qpk[PB[2*j]];
            const u32 d = pks(qa, qb);
            adp0 = pkmaxi(d, pks(0u, d));              // |d| per half, 0..7
            key[2*j] = pka(pkm(qa, EIGHTpk), qb);      // qa*8+qb per half
        }
        {
            const u32 qa = qpk[PA[2*j+1]], qb = qpk[PB[2*j+1]];
            const u32 d = pks(qa, qb);
            adp1 = pkmaxi(d, pks(0u, d));
            key[2*j+1] = pka(pkm(qa, EIGHTpk), qb);
        }
        // pack 4 |d| bytes: {adp0.ch0, adp0.ch1, adp1.ch0, adp1.ch1}
        const u32 pk4 = permb(adp1, adp0, 0x06040200u);
        // d^2 LUT {0,1,4,9 | 16,25,36,49}; byte-sum via sad
        csI  = sad8(permb(0x31241910u, 0x09040100u, pk4), z0, csI);
        // 840/(1+|d|) = {840,420,280,210,168,140,120,105}: lo/hi byte LUTs
        hloI = sad8(permb(0x69788CA8u, 0xD218A448u, pk4), z0, hloI);
        hhiI = sad8(permb(0x00000000u, 0x00010103u, pk4), z0, hhiI);
    }

    // Batcher odd-even mergesort for n=32, pruned to the low 20 slots
    #pragma unroll
    for (int p = 1; p < 32; p <<= 1) {
        #pragma unroll
        for (int k = p; k >= 1; k >>= 1) {
            const int jm = k % p;
            #pragma unroll
            for (int lo = 0; lo < 20; ++lo) {
                const int hi = lo + k;
                if (hi < 20 && lo >= jm && ((lo - jm) % (2 * k)) < k &&
                    (lo / (2 * p)) == (hi / (2 * p))) {
                    ce(key[lo], key[hi]);
                }
            }
        }
    }

    // boundary flags: eq[a] = (key[a]==key[a-1]) per half as 0/1 (packed)
    u32 eq[20];
    #pragma unroll
    for (int ai = 1; ai < 20; ++ai)
        eq[ai] = pks(ONEpk, pkmin(pks(key[ai], key[ai - 1]), ONEpk));

    // forward run scan: pc = (pc+1)*eq  (packed), psum += pc
    u32 pc = 0, ps = 0, pv[20];
    pv[0] = 0;
    #pragma unroll
    for (int ai = 1; ai < 20; ++ai) {
        pc = pkm(pka(pc, ONEpk), eq[ai]);
        pv[ai] = pc;
        ps = pka(ps, pc);
    }
    // backward run scan + multiplicity product: m = p + r + 1 (<=20, byte)
    float pr0, pr1;
    {
        const u32 m = pka(pv[19], ONEpk);
        pr0 = cb0(m); pr1 = cb2(m);
    }
    u32 rc = 0;
    #pragma unroll
    for (int ai = 18; ai >= 0; --ai) {
        rc = pkm(pka(rc, ONEpk), eq[ai + 1]);
        const u32 m = pka(pka(pv[ai], rc), ONEpk);
        pr0 *= cb0(m); pr1 *= cb2(m);
    }

    const int psum = (int)(ps & 0xFFFFu) + (int)(ps >> 16);
    // one log instead of two: scale each product by 2^-44 (stays in range:
    // max 20^20*2^-44 ~ 6e12, product <= 3.5e25; min 2^-88 ~ 3e-27)
    const float lsum = __logf((pr0 * 0x1p-44f) * (pr1 * 0x1p-44f))
                     + 60.9969518893f;                 // 88*ln2

    float fc = (float)csI * (1.f / 20.f);                // contrast (both ch)
    float fe = ((float)psum * 2.f + 40.f) * (1.f / 400.f);
    float fn = -(lsum + 40.f * -2.9957322736f) * (1.f / 20.f);
    float fh = (float)(hloI + (hhiI << 8)) * (1.f / 16800.f);  // /840/20

    // reduce over 4 ch-pairs within the wave (lane bits 4,5), then LDS
    // atomics across the 8 waves (no barrier, no reduce pass)
    fc += __shfl_xor(fc, 16); fe += __shfl_xor(fe, 16);
    fn += __shfl_xor(fn, 16); fh += __shfl_xor(fh, 16);
    fc += __shfl_xor(fc, 32); fe += __shfl_xor(fe, 32);
    fn += __shfl_xor(fn, 32); fh += __shfl_xor(fh, 32);
    if ((t & 63) < 16) {                 // one lane per px per wave
        atomicAdd(&xs[pxl][64], fc * 0.015625f);   // /64 channel mean
        atomicAdd(&xs[pxl][65], fe * 0.015625f);
        atomicAdd(&xs[pxl][66], fn * 0.015625f);
        atomicAdd(&xs[pxl][67], fh * 0.015625f);
    }
    __syncthreads();   // xs (x centers + g) complete (ds atomics drained)

    // ---- phase 2: cv1 + cv2, thread = (px, oc). float4 LDS reads, f32x2
    //      accumulation (compiler -> v_pk_fma_f32). Global stores DEFERRED. ----
    const int px = t & 15;
    const int oc = t >> 4;               // 0..31
    float v1out, v2out;
    {
        f32x2 a1l = {0.f, 0.f}, a1h = {0.f, 0.f};
        f32x2 a2l = {0.f, 0.f}, a2h = {0.f, 0.f};
        #pragma unroll
        for (int k = 0; k < 17; ++k) {
            const float4 xv = *reinterpret_cast<const float4*>(&xs[px][k * 4]);
            const float4 wa = *reinterpret_cast<const float4*>(&ws1[oc][k * 4]);
            const float4 wb = *reinterpret_cast<const float4*>(&ws2[oc][k * 4]);
            const f32x2 xl = {xv.x, xv.y}, xh = {xv.z, xv.w};
            a1l += xl * (f32x2){wa.x, wa.y};
            a1h += xh * (f32x2){wa.z, wa.w};
            a2l += xl * (f32x2){wb.x, wb.y};
            a2h += xh * (f32x2){wb.z, wb.w};
        }
        const float acc1 = a1l.x + a1l.y + a1h.x + a1h.y;
        const float acc2 = a2l.x + a2l.y + a2h.x + a2h.y;
        v1out = silu(acc1 * s1[oc] + b1[oc]);
        v2out = silu(acc2 * s2[oc] + b2[oc]);
        aT[px][oc] = v1out;              // LDS only before the barrier
    }
    __syncthreads();                     // drains lgkm only (no global stores)

    // ---- phase 3: m1 (f32x2), thread = (px, oc16), first 256 threads ----
    float ymout = 0.f;
    if (t < 256) {
        const int oc16 = t >> 4;
        f32x2 A = {0.f, 0.f};
        #pragma unroll
        for (int k = 0; k < 16; ++k) {
            const f32x2 av = *reinterpret_cast<const f32x2*>(&aT[px][k * 2]);
            const f32x2 wv2 = *reinterpret_cast<const f32x2*>(&wsm1[oc16][k * 2]);
            A += av * wv2;
        }
        ymout = silu((A.x + A.y) * sm1[oc16] + bm1[oc16]);
    }

    // ---- deferred global stores (drain at kernel end, not at a barrier) ----
    {
        const int hw2 = hw0 + px;
        a[((size_t)(bb * 32 + oc)) * HW + hw2]    = v1out;
        bbuf[((size_t)(bb * 32 + oc)) * HW + hw2] = v2out;
        if (t < 256)
            y16[((size_t)(bb * 16 + (t >> 4))) * HW + hw2] = ymout;
    }
}

// ---------------------------------------------------------------------------
// Kernel 2: m2 (3x3, 16->32, pad 1) + BN + SiLU + residual, then cv3
// (1x1, 64->64). The proven 512-thread 8-wave structure. Frozen.
// ---------------------------------------------------------------------------
__global__ __launch_bounds__(512) void m2cv3_kernel(
    const float* __restrict__ y16, const float* __restrict__ a,
    const float* __restrict__ bbuf,
    const float* __restrict__ wm2, const float* __restrict__ sm2, const float* __restrict__ bm2,
    const float* __restrict__ wc, const float* __restrict__ sc, const float* __restrict__ bc,
    float* __restrict__ out) {
    __shared__ float ys[16][4][82];
    __shared__ float a2[32][64];
    __shared__ float bs[32][64];
    const int t = threadIdx.x;
    const int p0 = blockIdx.x * 64;
    const int bi = p0 / HW;
    const int hw0 = p0 - bi * HW;
    const int h0 = hw0 / W;

    const float* yb = y16 + (size_t)(bi * 16) * HW;
    for (int e = t; e < 16 * 4 * 82; e += 512) {
        const int ch = e / 328;
        const int rem = e - ch * 328;
        const int row = rem / 82;
        const int col = rem - row * 82;
        const int r = h0 - 1 + row;
        const int c = col - 1;
        float v = 0.f;
        if ((unsigned)r < (unsigned)H && (unsigned)c < (unsigned)W)
            v = yb[(size_t)ch * HW + r * W + c];
        ys[ch][row][col] = v;
    }
    for (int e = t; e < 32 * 64; e += 512) {
        const int ic = e >> 6, px = e & 63;
        bs[ic][px] = bbuf[((size_t)(bi * 32 + ic)) * HW + hw0 + px];
    }
    __syncthreads();

    const int lane = t & 63;
    const int wv = __builtin_amdgcn_readfirstlane(t >> 6);
    const int hw = hw0 + lane;
    const int h = hw / W;
    const int w = hw - h * W;
    const int lr = h - h0;
    const int oc0 = wv * 4;

    float acc[4] = {0.f, 0.f, 0.f, 0.f};
    #pragma unroll 2
    for (int ic = 0; ic < 16; ++ic) {
        #pragma unroll
        for (int ky = 0; ky < 3; ++ky) {
            #pragma unroll
            for (int kx = 0; kx < 3; ++kx) {
                const float v = ys[ic][lr + ky][w + kx];
                const int tap = ic * 9 + ky * 3 + kx;
                #pragma unroll
                for (int j = 0; j < 4; ++j)
                    acc[j] += v * wm2[(oc0 + j) * 144 + tap];
            }
        }
    }
    #pragma unroll
    for (int j = 0; j < 4; ++j) {
        const int oc = oc0 + j;
        a2[oc][lane] = a[((size_t)(bi * 32 + oc)) * HW + hw]
                     + silu(acc[j] * sm2[oc] + bm2[oc]);
    }
    __syncthreads();
    const int oc3 = wv * 8;
    float c_[8] = {0.f, 0.f, 0.f, 0.f, 0.f, 0.f, 0.f, 0.f};
    #pragma unroll 4
    for (int ic = 0; ic < 32; ++ic) {
        const float av = a2[ic][lane];
        const float bv = bs[ic][lane];
        #pragma unroll
        for (int j = 0; j < 8; ++j) {
            c_[j] += av * wc[(oc3 + j) * 64 + ic];
            c_[j] += bv * wc[(oc3 + j) * 64 + 32 + ic];
        }
    }
    #pragma unroll
    for (int j = 0; j < 8; ++j) {
        const int oc = oc3 + j;
        out[((size_t)(bi * 64 + oc)) * HW + hw] = silu(c_[j] * sc[oc] + bc[oc]);
    }
}

// ---------------------------------------------------------------------------
extern "C" void kernel_launch(void* const* d_in, const int* in_sizes, int n_in,
                              void* d_out, int out_size, void* d_ws, size_t ws_size,
                              hipStream_t stream) {
    const float* x    = (const float*)d_in[0];
    const float* cv1w = (const float*)d_in[1];
    const float* cv1s = (const float*)d_in[2];
    const float* cv1b = (const float*)d_in[3];
    const float* cv2w = (const float*)d_in[4];
    const float* cv2s = (const float*)d_in[5];
    const float* cv2b = (const float*)d_in[6];
    const float* m1w  = (const float*)d_in[7];
    const float* m1s  = (const float*)d_in[8];
    const float* m1b  = (const float*)d_in[9];
    const float* m2w  = (const float*)d_in[10];
    const float* m2s  = (const float*)d_in[11];
    const float* m2b  = (const float*)d_in[12];
    const float* cv3w = (const float*)d_in[13];
    const float* cv3s = (const float*)d_in[14];
    const float* cv3b = (const float*)d_in[15];

    float* ws   = (float*)d_ws;
    float* a    = ws;                 // 4*32*6400 = 819200
    float* bbuf = ws + 819200;        // 819200
    float* y16  = ws + 1638400;       // 409600 (end 2048000)

    glcm_stage1_kernel<<<NTILE1, 512, 0, stream>>>(
        x, cv1w, cv1s, cv1b, cv2w, cv2s, cv2b, m1w, m1s, m1b, a, bbuf, y16);
    m2cv3_kernel<<<NTILE2, 512, 0, stream>>>(
        y16, a, bbuf, m2w, m2s, m2b, cv3w, cv3s, cv3b, (float*)d_out);
}

// Round 20
// 52.876 us; speedup vs baseline: 1.0700x; 1.0691x over previous
//
#include <hip/hip_runtime.h>
#include <math.h>

constexpr int B = 4, C = 64, H = 80, W = 80;
constexpr int HW = H * W;            // 6400
constexpr int NPIX = B * HW;         // 25600
constexpr int PXB = 16;              // pixels per block (16 | W=80)
constexpr int NTILE1 = NPIX / PXB;   // 1600 stage1 blocks (plain launch —
                                     // R13-R16: every alternative regressed)
constexpr int NTILE2 = NPIX / 64;    // 400 m2cv3 blocks

typedef unsigned u32;
typedef float f32x2 __attribute__((ext_vector_type(2)));

static __device__ __forceinline__ float silu(float v) {
    float e = __expf(-v);
    return v * __builtin_amdgcn_rcpf(1.0f + e);
}

// ---- packed u16 helpers (both GLCM channels in one instruction) -----------
static __device__ __forceinline__ u32 pks(u32 a, u32 b){u32 d; asm("v_pk_sub_u16 %0,%1,%2":"=v"(d):"v"(a),"v"(b)); return d;}
static __device__ __forceinline__ u32 pka(u32 a, u32 b){u32 d; asm("v_pk_add_u16 %0,%1,%2":"=v"(d):"v"(a),"v"(b)); return d;}
static __device__ __forceinline__ u32 pkm(u32 a, u32 b){u32 d; asm("v_pk_mul_lo_u16 %0,%1,%2":"=v"(d):"v"(a),"v"(b)); return d;}
static __device__ __forceinline__ u32 pkmin(u32 a, u32 b){u32 d; asm("v_pk_min_u16 %0,%1,%2":"=v"(d):"v"(a),"v"(b)); return d;}
static __device__ __forceinline__ u32 pkmaxi(u32 a, u32 b){u32 d; asm("v_pk_max_i16 %0,%1,%2":"=v"(d):"v"(a),"v"(b)); return d;}
static __device__ __forceinline__ float cb0(u32 a){float f; asm("v_cvt_f32_ubyte0 %0,%1":"=v"(f):"v"(a)); return f;}
static __device__ __forceinline__ float cb2(u32 a){float f; asm("v_cvt_f32_ubyte2 %0,%1":"=v"(f):"v"(a)); return f;}

// byte shuffle/LUT and byte-sum
static __device__ __forceinline__ u32 permb(u32 hi, u32 lo, u32 sel){
    u32 d; asm("v_perm_b32 %0, %1, %2, %3" : "=v"(d) : "v"(hi), "v"(lo), "v"(sel)); return d;}
static __device__ __forceinline__ u32 sad8(u32 a, u32 b, u32 c){
    u32 d; asm("v_sad_u8 %0, %1, %2, %3" : "=v"(d) : "v"(a), "v"(b), "v"(c)); return d;}

// packed compare-exchange: both u16 halves sorted independently (2 channels)
static __device__ __forceinline__ void ce(u32 &x, u32 &y) {
    u32 mn, mx;
    asm("v_pk_min_u16 %0, %2, %3\n\t"
        "v_pk_max_u16 %1, %2, %3"
        : "=&v"(mn), "=v"(mx) : "v"(x), "v"(y));
    x = mn; y = mx;
}

// ---------------------------------------------------------------------------
// Kernel 1: GLCM + cv1 + cv2 + m1 fused. Byte-identical to the R19 build
// (best stage1 measurement: 40.12 µs, VALUBusy 45.8%, Occ 53%).
// ---------------------------------------------------------------------------
__global__ __launch_bounds__(512, 4) void glcm_stage1_kernel(
    const float* __restrict__ x,
    const float* __restrict__ w1, const float* __restrict__ s1, const float* __restrict__ b1,
    const float* __restrict__ w2, const float* __restrict__ s2, const float* __restrict__ b2,
    const float* __restrict__ wm1, const float* __restrict__ sm1, const float* __restrict__ bm1,
    float* __restrict__ a, float* __restrict__ bbuf, float* __restrict__ y16) {
    __shared__ u32 qcell[32][3][18];              // packed quantized stencil rows
    __shared__ __align__(16) float xs[PXB][76];   // [px][68 ic + 4 g], pad 76
    __shared__ __align__(16) float ws1[32][68];   // cv1 weights, natural layout
    __shared__ __align__(16) float ws2[32][68];
    __shared__ __align__(16) float wsm1[16][32];
    __shared__ __align__(16) float aT[PXB][34];   // cv1 out tile (b64-aligned)

    const int t = threadIdx.x;
    const int p0g = blockIdx.x * PXB;
    const int bb  = p0g / HW;
    const int hw0 = p0g - bb * HW;
    const int h0  = hw0 / W;
    const int c0g = hw0 - h0 * W;        // col base (block is 16 px in one row)

    // ---- phase 0a: weights -> LDS; zero the g accumulators ----
    {
        const float4* w1f = (const float4*)w1;
        const float4* w2f = (const float4*)w2;
        float4* s1f = (float4*)&ws1[0][0];
        float4* s2f = (float4*)&ws2[0][0];
        for (int e = t; e < 544; e += 512) { s1f[e] = w1f[e]; s2f[e] = w2f[e]; }
        if (t < 128) ((float4*)&wsm1[0][0])[t] = ((const float4*)wm1)[t];
        if (t < 64) xs[t >> 2][64 + (t & 3)] = 0.f;   // g accum zero-init
    }
    // ---- phase 0b: quantize stencil rows once, pack both channels ----
    for (int e = t; e < 32 * 3 * 18; e += 512) {
        const int grp = e / 54;
        const int rem = e - grp * 54;
        const int row = rem / 18;        // 0..2  (image rows h0-1..h0+1, clamped)
        const int col = rem - row * 18;  // 0..17 (image cols c0g-1..c0g+16, clamped)
        int gr = h0 + row - 1;  gr = gr < 0 ? 0 : (gr > H - 1 ? H - 1 : gr);
        int gc = c0g + col - 1; gc = gc < 0 ? 0 : (gc > W - 1 ? W - 1 : gc);
        const float v0 = x[((size_t)(bb * C + grp * 2)) * HW + gr * W + gc];
        const float v1 = x[((size_t)(bb * C + grp * 2 + 1)) * HW + gr * W + gc];
        int q0 = (int)(v0 * 7.0f); q0 = q0 < 0 ? 0 : (q0 > 7 ? 7 : q0);
        int q1 = (int)(v1 * 7.0f); q1 = q1 < 0 ? 0 : (q1 > 7 ? 7 : q1);
        qcell[grp][row][col] = (u32)q0 | ((u32)q1 << 16);
        if (row == 1 && col >= 1 && col <= 16) {   // raw centers for the convs
            xs[col - 1][grp * 2]     = v0;
            xs[col - 1][grp * 2 + 1] = v1;
        }
    }
    __syncthreads();

    // ---- phase 1: GLCM (packed-u16 core; 9 LDS reads, zero quantize) ----
    const int pxl = t & 15;              // 0..15
    const int grp = t >> 4;              // 0..31 (channel pair)
    u32 qpk[9];
    #pragma unroll
    for (int r = 0; r < 3; ++r)
        #pragma unroll
        for (int k = 0; k < 3; ++k)
            qpk[r * 3 + k] = qcell[grp][r][pxl + k];

    static constexpr int PA[20] = {0,1,3,4,6,7, 0,1,2,3,4,5, 0,1,3,4, 1,2,4,5};
    static constexpr int PB[20] = {1,2,4,5,7,8, 3,4,5,6,7,8, 4,5,7,8, 3,4,6,7};

    const u32 ONEpk = 0x00010001u, EIGHTpk = 0x00080008u;
    u32 key[20];
    u32 csI = 0, hloI = 0, hhiI = 0;     // integer byte-sums (both channels)
    const u32 z0 = 0;
    #pragma unroll
    for (int j = 0; j < 10; ++j) {
        u32 adp0, adp1;
        {
            const u32 qa = qpk[PA[2*j]], qb = qpk[PB[2*j]];
            const u32 d = pks(qa, qb);
            adp0 = pkmaxi(d, pks(0u, d));              // |d| per half, 0..7
            key[2*j] = pka(pkm(qa, EIGHTpk), qb);      // qa*8+qb per half
        }
        {
            const u32 qa = qpk[PA[2*j+1]], qb = qpk[PB[2*j+1]];
            const u32 d = pks(qa, qb);
            adp1 = pkmaxi(d, pks(0u, d));
            key[2*j+1] = pka(pkm(qa, EIGHTpk), qb);
        }
        // pack 4 |d| bytes: {adp0.ch0, adp0.ch1, adp1.ch0, adp1.ch1}
        const u32 pk4 = permb(adp1, adp0, 0x06040200u);
        // d^2 LUT {0,1,4,9 | 16,25,36,49}; byte-sum via sad
        csI  = sad8(permb(0x31241910u, 0x09040100u, pk4), z0, csI);
        // 840/(1+|d|) = {840,420,280,210,168,140,120,105}: lo/hi byte LUTs
        hloI = sad8(permb(0x69788CA8u, 0xD218A448u, pk4), z0, hloI);
        hhiI = sad8(permb(0x00000000u, 0x00010103u, pk4), z0, hhiI);
    }

    // Batcher odd-even mergesort for n=32, pruned to the low 20 slots
    #pragma unroll
    for (int p = 1; p < 32; p <<= 1) {
        #pragma unroll
        for (int k = p; k >= 1; k >>= 1) {
            const int jm = k % p;
            #pragma unroll
            for (int lo = 0; lo < 20; ++lo) {
                const int hi = lo + k;
                if (hi < 20 && lo >= jm && ((lo - jm) % (2 * k)) < k &&
                    (lo / (2 * p)) == (hi / (2 * p))) {
                    ce(key[lo], key[hi]);
                }
            }
        }
    }

    // boundary flags: eq[a] = (key[a]==key[a-1]) per half as 0/1 (packed)
    u32 eq[20];
    #pragma unroll
    for (int ai = 1; ai < 20; ++ai)
        eq[ai] = pks(ONEpk, pkmin(pks(key[ai], key[ai - 1]), ONEpk));

    // forward run scan: pc = (pc+1)*eq  (packed), psum += pc
    u32 pc = 0, ps = 0, pv[20];
    pv[0] = 0;
    #pragma unroll
    for (int ai = 1; ai < 20; ++ai) {
        pc = pkm(pka(pc, ONEpk), eq[ai]);
        pv[ai] = pc;
        ps = pka(ps, pc);
    }
    // backward run scan + multiplicity product: m = p + r + 1 (<=20, byte)
    float pr0, pr1;
    {
        const u32 m = pka(pv[19], ONEpk);
        pr0 = cb0(m); pr1 = cb2(m);
    }
    u32 rc = 0;
    #pragma unroll
    for (int ai = 18; ai >= 0; --ai) {
        rc = pkm(pka(rc, ONEpk), eq[ai + 1]);
        const u32 m = pka(pka(pv[ai], rc), ONEpk);
        pr0 *= cb0(m); pr1 *= cb2(m);
    }

    const int psum = (int)(ps & 0xFFFFu) + (int)(ps >> 16);
    // one log instead of two: scale each product by 2^-44 (stays in range)
    const float lsum = __logf((pr0 * 0x1p-44f) * (pr1 * 0x1p-44f))
                     + 60.9969518893f;                 // 88*ln2

    float fc = (float)csI * (1.f / 20.f);                // contrast (both ch)
    float fe = ((float)psum * 2.f + 40.f) * (1.f / 400.f);
    float fn = -(lsum + 40.f * -2.9957322736f) * (1.f / 20.f);
    float fh = (float)(hloI + (hhiI << 8)) * (1.f / 16800.f);  // /840/20

    // reduce over 4 ch-pairs within the wave (lane bits 4,5), then LDS
    // atomics across the 8 waves (no barrier, no reduce pass)
    fc += __shfl_xor(fc, 16); fe += __shfl_xor(fe, 16);
    fn += __shfl_xor(fn, 16); fh += __shfl_xor(fh, 16);
    fc += __shfl_xor(fc, 32); fe += __shfl_xor(fe, 32);
    fn += __shfl_xor(fn, 32); fh += __shfl_xor(fh, 32);
    if ((t & 63) < 16) {                 // one lane per px per wave
        atomicAdd(&xs[pxl][64], fc * 0.015625f);   // /64 channel mean
        atomicAdd(&xs[pxl][65], fe * 0.015625f);
        atomicAdd(&xs[pxl][66], fn * 0.015625f);
        atomicAdd(&xs[pxl][67], fh * 0.015625f);
    }
    __syncthreads();   // xs (x centers + g) complete (ds atomics drained)

    // ---- phase 2: cv1 + cv2, thread = (px, oc). float4 LDS reads, f32x2
    //      accumulation (compiler -> v_pk_fma_f32). Global stores DEFERRED. ----
    const int px = t & 15;
    const int oc = t >> 4;               // 0..31
    float v1out, v2out;
    {
        f32x2 a1l = {0.f, 0.f}, a1h = {0.f, 0.f};
        f32x2 a2l = {0.f, 0.f}, a2h = {0.f, 0.f};
        #pragma unroll
        for (int k = 0; k < 17; ++k) {
            const float4 xv = *reinterpret_cast<const float4*>(&xs[px][k * 4]);
            const float4 wa = *reinterpret_cast<const float4*>(&ws1[oc][k * 4]);
            const float4 wb = *reinterpret_cast<const float4*>(&ws2[oc][k * 4]);
            const f32x2 xl = {xv.x, xv.y}, xh = {xv.z, xv.w};
            a1l += xl * (f32x2){wa.x, wa.y};
            a1h += xh * (f32x2){wa.z, wa.w};
            a2l += xl * (f32x2){wb.x, wb.y};
            a2h += xh * (f32x2){wb.z, wb.w};
        }
        const float acc1 = a1l.x + a1l.y + a1h.x + a1h.y;
        const float acc2 = a2l.x + a2l.y + a2h.x + a2h.y;
        v1out = silu(acc1 * s1[oc] + b1[oc]);
        v2out = silu(acc2 * s2[oc] + b2[oc]);
        aT[px][oc] = v1out;              // LDS only before the barrier
    }
    __syncthreads();                     // drains lgkm only (no global stores)

    // ---- phase 3: m1 (f32x2), thread = (px, oc16), first 256 threads ----
    float ymout = 0.f;
    if (t < 256) {
        const int oc16 = t >> 4;
        f32x2 A = {0.f, 0.f};
        #pragma unroll
        for (int k = 0; k < 16; ++k) {
            const f32x2 av = *reinterpret_cast<const f32x2*>(&aT[px][k * 2]);
            const f32x2 wv2 = *reinterpret_cast<const f32x2*>(&wsm1[oc16][k * 2]);
            A += av * wv2;
        }
        ymout = silu((A.x + A.y) * sm1[oc16] + bm1[oc16]);
    }

    // ---- deferred global stores (drain at kernel end, not at a barrier) ----
    {
        const int hw2 = hw0 + px;
        a[((size_t)(bb * 32 + oc)) * HW + hw2]    = v1out;
        bbuf[((size_t)(bb * 32 + oc)) * HW + hw2] = v2out;
        if (t < 256)
            y16[((size_t)(bb * 16 + (t >> 4))) * HW + hw2] = ymout;
    }
}

// ---------------------------------------------------------------------------
// Kernel 2: m2 (3x3, 16->32, pad 1) + BN + SiLU + residual, then cv3
// (1x1, 64->64). R20 change: float4 staging.
//  - ys re-laid out as [16][4][88], interior at col offset +4 (16B-aligned
//    b128 stores); halo COLS (c=-1, c=80) are always outside W -> statically
//    zero; out-of-image ROWS zero-filled vectorized.
//  - bs staged as float4 (hw0 is 64-aligned -> aligned global loads).
// Staging issue-ops: ~4224 scalar -> ~1408 vector + 128 zeroes per block.
// LDS 38.9 KB -> still 4 blocks/CU. Compute phases unchanged.
// ---------------------------------------------------------------------------
__global__ __launch_bounds__(512) void m2cv3_kernel(
    const float* __restrict__ y16, const float* __restrict__ a,
    const float* __restrict__ bbuf,
    const float* __restrict__ wm2, const float* __restrict__ sm2, const float* __restrict__ bm2,
    const float* __restrict__ wc, const float* __restrict__ sc, const float* __restrict__ bc,
    float* __restrict__ out) {
    __shared__ __align__(16) float ys[16][4][88];  // interior at [.][.][4..83]
    __shared__ __align__(16) float a2[32][64];
    __shared__ __align__(16) float bs[32][64];
    const int t = threadIdx.x;
    const int p0 = blockIdx.x * 64;
    const int bi = p0 / HW;
    const int hw0 = p0 - bi * HW;
    const int h0 = hw0 / W;

    // halo columns: always outside the image (zero-pad conv) -> zero them
    if (t < 128) {
        const int ch = t >> 3, row = (t >> 1) & 3, side = t & 1;
        ys[ch][row][side ? 84 : 3] = 0.f;
    }
    // interior: 16 ch x 4 rows x 20 float4 (row r = h0-1+row; zero if OOB)
    const float* yb = y16 + (size_t)(bi * 16) * HW;
    for (int e = t; e < 16 * 4 * 20; e += 512) {
        const int ch = e / 80;
        const int rem = e - ch * 80;
        const int row = rem / 20;
        const int k4 = rem - row * 20;
        const int r = h0 - 1 + row;
        float4 v = {0.f, 0.f, 0.f, 0.f};
        if ((unsigned)r < (unsigned)H)
            v = *reinterpret_cast<const float4*>(&yb[(size_t)ch * HW + r * W + k4 * 4]);
        *reinterpret_cast<float4*>(&ys[ch][row][4 + k4 * 4]) = v;
    }
    // bs: 32 ch x 16 float4 (aligned: hw0 is a multiple of 64)
    if (t < 512) {
        const int ic = t >> 4, k4 = t & 15;
        *reinterpret_cast<float4*>(&bs[ic][k4 * 4]) =
            *reinterpret_cast<const float4*>(&bbuf[((size_t)(bi * 32 + ic)) * HW + hw0 + k4 * 4]);
    }
    __syncthreads();

    const int lane = t & 63;
    const int wv = __builtin_amdgcn_readfirstlane(t >> 6);
    const int hw = hw0 + lane;
    const int h = hw / W;
    const int w = hw - h * W;
    const int lr = h - h0;
    const int oc0 = wv * 4;

    float acc[4] = {0.f, 0.f, 0.f, 0.f};
    #pragma unroll 2
    for (int ic = 0; ic < 16; ++ic) {
        #pragma unroll
        for (int ky = 0; ky < 3; ++ky) {
            #pragma unroll
            for (int kx = 0; kx < 3; ++kx) {
                const float v = ys[ic][lr + ky][3 + w + kx];
                const int tap = ic * 9 + ky * 3 + kx;
                #pragma unroll
                for (int j = 0; j < 4; ++j)
                    acc[j] += v * wm2[(oc0 + j) * 144 + tap];
            }
        }
    }
    #pragma unroll
    for (int j = 0; j < 4; ++j) {
        const int oc = oc0 + j;
        a2[oc][lane] = a[((size_t)(bi * 32 + oc)) * HW + hw]
                     + silu(acc[j] * sm2[oc] + bm2[oc]);
    }
    __syncthreads();
    const int oc3 = wv * 8;
    float c_[8] = {0.f, 0.f, 0.f, 0.f, 0.f, 0.f, 0.f, 0.f};
    #pragma unroll 4
    for (int ic = 0; ic < 32; ++ic) {
        const float av = a2[ic][lane];
        const float bv = bs[ic][lane];
        #pragma unroll
        for (int j = 0; j < 8; ++j) {
            c_[j] += av * wc[(oc3 + j) * 64 + ic];
            c_[j] += bv * wc[(oc3 + j) * 64 + 32 + ic];
        }
    }
    #pragma unroll
    for (int j = 0; j < 8; ++j) {
        const int oc = oc3 + j;
        out[((size_t)(bi * 64 + oc)) * HW + hw] = silu(c_[j] * sc[oc] + bc[oc]);
    }
}

// ---------------------------------------------------------------------------
extern "C" void kernel_launch(void* const* d_in, const int* in_sizes, int n_in,
                              void* d_out, int out_size, void* d_ws, size_t ws_size,
                              hipStream_t stream) {
    const float* x    = (const float*)d_in[0];
    const float* cv1w = (const float*)d_in[1];
    const float* cv1s = (const float*)d_in[2];
    const float* cv1b = (const float*)d_in[3];
    const float* cv2w = (const float*)d_in[4];
    const float* cv2s = (const float*)d_in[5];
    const float* cv2b = (const float*)d_in[6];
    const float* m1w  = (const float*)d_in[7];
    const float* m1s  = (const float*)d_in[8];
    const float* m1b  = (const float*)d_in[9];
    const float* m2w  = (const float*)d_in[10];
    const float* m2s  = (const float*)d_in[11];
    const float* m2b  = (const float*)d_in[12];
    const float* cv3w = (const float*)d_in[13];
    const float* cv3s = (const float*)d_in[14];
    const float* cv3b = (const float*)d_in[15];

    float* ws   = (float*)d_ws;
    float* a    = ws;                 // 4*32*6400 = 819200
    float* bbuf = ws + 819200;        // 819200
    float* y16  = ws + 1638400;       // 409600 (end 2048000)

    glcm_stage1_kernel<<<NTILE1, 512, 0, stream>>>(
        x, cv1w, cv1s, cv1b, cv2w, cv2s, cv2b, m1w, m1s, m1b, a, bbuf, y16);
    m2cv3_kernel<<<NTILE2, 512, 0, stream>>>(
        y16, a, bbuf, m2w, m2s, m2b, cv3w, cv3s, cv3b, (float*)d_out);
}

// Round 21
// 52.361 us; speedup vs baseline: 1.0805x; 1.0098x over previous
//
#include <hip/hip_runtime.h>
#include <math.h>

constexpr int B = 4, C = 64, H = 80, W = 80;
constexpr int HW = H * W;            // 6400
constexpr int NPIX = B * HW;         // 25600
constexpr int PXB = 16;              // pixels per block (16 | W=80)
constexpr int NTILE1 = NPIX / PXB;   // 1600 stage1 blocks (plain launch —
                                     // R13-R16: every alternative regressed)
constexpr int NTILE2 = NPIX / 64;    // 400 m2cv3 blocks

typedef unsigned u32;
typedef float f32x2 __attribute__((ext_vector_type(2)));

static __device__ __forceinline__ float silu(float v) {
    float e = __expf(-v);
    return v * __builtin_amdgcn_rcpf(1.0f + e);
}

// ---- packed u16 helpers (both GLCM channels in one instruction) -----------
static __device__ __forceinline__ u32 pks(u32 a, u32 b){u32 d; asm("v_pk_sub_u16 %0,%1,%2":"=v"(d):"v"(a),"v"(b)); return d;}
static __device__ __forceinline__ u32 pka(u32 a, u32 b){u32 d; asm("v_pk_add_u16 %0,%1,%2":"=v"(d):"v"(a),"v"(b)); return d;}
static __device__ __forceinline__ u32 pkm(u32 a, u32 b){u32 d; asm("v_pk_mul_lo_u16 %0,%1,%2":"=v"(d):"v"(a),"v"(b)); return d;}
static __device__ __forceinline__ u32 pkmin(u32 a, u32 b){u32 d; asm("v_pk_min_u16 %0,%1,%2":"=v"(d):"v"(a),"v"(b)); return d;}
static __device__ __forceinline__ u32 pkmaxi(u32 a, u32 b){u32 d; asm("v_pk_max_i16 %0,%1,%2":"=v"(d):"v"(a),"v"(b)); return d;}
static __device__ __forceinline__ float cb0(u32 a){float f; asm("v_cvt_f32_ubyte0 %0,%1":"=v"(f):"v"(a)); return f;}
static __device__ __forceinline__ float cb2(u32 a){float f; asm("v_cvt_f32_ubyte2 %0,%1":"=v"(f):"v"(a)); return f;}

// byte shuffle/LUT and byte-sum
static __device__ __forceinline__ u32 permb(u32 hi, u32 lo, u32 sel){
    u32 d; asm("v_perm_b32 %0, %1, %2, %3" : "=v"(d) : "v"(hi), "v"(lo), "v"(sel)); return d;}
static __device__ __forceinline__ u32 sad8(u32 a, u32 b, u32 c){
    u32 d; asm("v_sad_u8 %0, %1, %2, %3" : "=v"(d) : "v"(a), "v"(b), "v"(c)); return d;}

// packed compare-exchange: both u16 halves sorted independently (2 channels)
static __device__ __forceinline__ void ce(u32 &x, u32 &y) {
    u32 mn, mx;
    asm("v_pk_min_u16 %0, %2, %3\n\t"
        "v_pk_max_u16 %1, %2, %3"
        : "=&v"(mn), "=v"(mx) : "v"(x), "v"(y));
    x = mn; y = mx;
}

// ---------------------------------------------------------------------------
// Kernel 1: GLCM + cv1 + cv2 + m1 fused. Byte-identical to the R19 build
// (best stage1 measurement: 40.12 µs). FROZEN.
// ---------------------------------------------------------------------------
__global__ __launch_bounds__(512, 4) void glcm_stage1_kernel(
    const float* __restrict__ x,
    const float* __restrict__ w1, const float* __restrict__ s1, const float* __restrict__ b1,
    const float* __restrict__ w2, const float* __restrict__ s2, const float* __restrict__ b2,
    const float* __restrict__ wm1, const float* __restrict__ sm1, const float* __restrict__ bm1,
    float* __restrict__ a, float* __restrict__ bbuf, float* __restrict__ y16) {
    __shared__ u32 qcell[32][3][18];              // packed quantized stencil rows
    __shared__ __align__(16) float xs[PXB][76];   // [px][68 ic + 4 g], pad 76
    __shared__ __align__(16) float ws1[32][68];   // cv1 weights, natural layout
    __shared__ __align__(16) float ws2[32][68];
    __shared__ __align__(16) float wsm1[16][32];
    __shared__ __align__(16) float aT[PXB][34];   // cv1 out tile (b64-aligned)

    const int t = threadIdx.x;
    const int p0g = blockIdx.x * PXB;
    const int bb  = p0g / HW;
    const int hw0 = p0g - bb * HW;
    const int h0  = hw0 / W;
    const int c0g = hw0 - h0 * W;        // col base (block is 16 px in one row)

    // ---- phase 0a: weights -> LDS; zero the g accumulators ----
    {
        const float4* w1f = (const float4*)w1;
        const float4* w2f = (const float4*)w2;
        float4* s1f = (float4*)&ws1[0][0];
        float4* s2f = (float4*)&ws2[0][0];
        for (int e = t; e < 544; e += 512) { s1f[e] = w1f[e]; s2f[e] = w2f[e]; }
        if (t < 128) ((float4*)&wsm1[0][0])[t] = ((const float4*)wm1)[t];
        if (t < 64) xs[t >> 2][64 + (t & 3)] = 0.f;   // g accum zero-init
    }
    // ---- phase 0b: quantize stencil rows once, pack both channels ----
    for (int e = t; e < 32 * 3 * 18; e += 512) {
        const int grp = e / 54;
        const int rem = e - grp * 54;
        const int row = rem / 18;        // 0..2  (image rows h0-1..h0+1, clamped)
        const int col = rem - row * 18;  // 0..17 (image cols c0g-1..c0g+16, clamped)
        int gr = h0 + row - 1;  gr = gr < 0 ? 0 : (gr > H - 1 ? H - 1 : gr);
        int gc = c0g + col - 1; gc = gc < 0 ? 0 : (gc > W - 1 ? W - 1 : gc);
        const float v0 = x[((size_t)(bb * C + grp * 2)) * HW + gr * W + gc];
        const float v1 = x[((size_t)(bb * C + grp * 2 + 1)) * HW + gr * W + gc];
        int q0 = (int)(v0 * 7.0f); q0 = q0 < 0 ? 0 : (q0 > 7 ? 7 : q0);
        int q1 = (int)(v1 * 7.0f); q1 = q1 < 0 ? 0 : (q1 > 7 ? 7 : q1);
        qcell[grp][row][col] = (u32)q0 | ((u32)q1 << 16);
        if (row == 1 && col >= 1 && col <= 16) {   // raw centers for the convs
            xs[col - 1][grp * 2]     = v0;
            xs[col - 1][grp * 2 + 1] = v1;
        }
    }
    __syncthreads();

    // ---- phase 1: GLCM (packed-u16 core; 9 LDS reads, zero quantize) ----
    const int pxl = t & 15;              // 0..15
    const int grp = t >> 4;              // 0..31 (channel pair)
    u32 qpk[9];
    #pragma unroll
    for (int r = 0; r < 3; ++r)
        #pragma unroll
        for (int k = 0; k < 3; ++k)
            qpk[r * 3 + k] = qcell[grp][r][pxl + k];

    static constexpr int PA[20] = {0,1,3,4,6,7, 0,1,2,3,4,5, 0,1,3,4, 1,2,4,5};
    static constexpr int PB[20] = {1,2,4,5,7,8, 3,4,5,6,7,8, 4,5,7,8, 3,4,6,7};

    const u32 ONEpk = 0x00010001u, EIGHTpk = 0x00080008u;
    u32 key[20];
    u32 csI = 0, hloI = 0, hhiI = 0;     // integer byte-sums (both channels)
    const u32 z0 = 0;
    #pragma unroll
    for (int j = 0; j < 10; ++j) {
        u32 adp0, adp1;
        {
            const u32 qa = qpk[PA[2*j]], qb = qpk[PB[2*j]];
            const u32 d = pks(qa, qb);
            adp0 = pkmaxi(d, pks(0u, d));              // |d| per half, 0..7
            key[2*j] = pka(pkm(qa, EIGHTpk), qb);      // qa*8+qb per half
        }
        {
            const u32 qa = qpk[PA[2*j+1]], qb = qpk[PB[2*j+1]];
            const u32 d = pks(qa, qb);
            adp1 = pkmaxi(d, pks(0u, d));
            key[2*j+1] = pka(pkm(qa, EIGHTpk), qb);
        }
        // pack 4 |d| bytes: {adp0.ch0, adp0.ch1, adp1.ch0, adp1.ch1}
        const u32 pk4 = permb(adp1, adp0, 0x06040200u);
        // d^2 LUT {0,1,4,9 | 16,25,36,49}; byte-sum via sad
        csI  = sad8(permb(0x31241910u, 0x09040100u, pk4), z0, csI);
        // 840/(1+|d|) = {840,420,280,210,168,140,120,105}: lo/hi byte LUTs
        hloI = sad8(permb(0x69788CA8u, 0xD218A448u, pk4), z0, hloI);
        hhiI = sad8(permb(0x00000000u, 0x00010103u, pk4), z0, hhiI);
    }

    // Batcher odd-even mergesort for n=32, pruned to the low 20 slots
    #pragma unroll
    for (int p = 1; p < 32; p <<= 1) {
        #pragma unroll
        for (int k = p; k >= 1; k >>= 1) {
            const int jm = k % p;
            #pragma unroll
            for (int lo = 0; lo < 20; ++lo) {
                const int hi = lo + k;
                if (hi < 20 && lo >= jm && ((lo - jm) % (2 * k)) < k &&
                    (lo / (2 * p)) == (hi / (2 * p))) {
                    ce(key[lo], key[hi]);
                }
            }
        }
    }

    // boundary flags: eq[a] = (key[a]==key[a-1]) per half as 0/1 (packed)
    u32 eq[20];
    #pragma unroll
    for (int ai = 1; ai < 20; ++ai)
        eq[ai] = pks(ONEpk, pkmin(pks(key[ai], key[ai - 1]), ONEpk));

    // forward run scan: pc = (pc+1)*eq  (packed), psum += pc
    u32 pc = 0, ps = 0, pv[20];
    pv[0] = 0;
    #pragma unroll
    for (int ai = 1; ai < 20; ++ai) {
        pc = pkm(pka(pc, ONEpk), eq[ai]);
        pv[ai] = pc;
        ps = pka(ps, pc);
    }
    // backward run scan + multiplicity product: m = p + r + 1 (<=20, byte)
    float pr0, pr1;
    {
        const u32 m = pka(pv[19], ONEpk);
        pr0 = cb0(m); pr1 = cb2(m);
    }
    u32 rc = 0;
    #pragma unroll
    for (int ai = 18; ai >= 0; --ai) {
        rc = pkm(pka(rc, ONEpk), eq[ai + 1]);
        const u32 m = pka(pka(pv[ai], rc), ONEpk);
        pr0 *= cb0(m); pr1 *= cb2(m);
    }

    const int psum = (int)(ps & 0xFFFFu) + (int)(ps >> 16);
    // one log instead of two: scale each product by 2^-44 (stays in range)
    const float lsum = __logf((pr0 * 0x1p-44f) * (pr1 * 0x1p-44f))
                     + 60.9969518893f;                 // 88*ln2

    float fc = (float)csI * (1.f / 20.f);                // contrast (both ch)
    float fe = ((float)psum * 2.f + 40.f) * (1.f / 400.f);
    float fn = -(lsum + 40.f * -2.9957322736f) * (1.f / 20.f);
    float fh = (float)(hloI + (hhiI << 8)) * (1.f / 16800.f);  // /840/20

    // reduce over 4 ch-pairs within the wave (lane bits 4,5), then LDS
    // atomics across the 8 waves (no barrier, no reduce pass)
    fc += __shfl_xor(fc, 16); fe += __shfl_xor(fe, 16);
    fn += __shfl_xor(fn, 16); fh += __shfl_xor(fh, 16);
    fc += __shfl_xor(fc, 32); fe += __shfl_xor(fe, 32);
    fn += __shfl_xor(fn, 32); fh += __shfl_xor(fh, 32);
    if ((t & 63) < 16) {                 // one lane per px per wave
        atomicAdd(&xs[pxl][64], fc * 0.015625f);   // /64 channel mean
        atomicAdd(&xs[pxl][65], fe * 0.015625f);
        atomicAdd(&xs[pxl][66], fn * 0.015625f);
        atomicAdd(&xs[pxl][67], fh * 0.015625f);
    }
    __syncthreads();   // xs (x centers + g) complete (ds atomics drained)

    // ---- phase 2: cv1 + cv2, thread = (px, oc). float4 LDS reads, f32x2
    //      accumulation (compiler -> v_pk_fma_f32). Global stores DEFERRED. ----
    const int px = t & 15;
    const int oc = t >> 4;               // 0..31
    float v1out, v2out;
    {
        f32x2 a1l = {0.f, 0.f}, a1h = {0.f, 0.f};
        f32x2 a2l = {0.f, 0.f}, a2h = {0.f, 0.f};
        #pragma unroll
        for (int k = 0; k < 17; ++k) {
            const float4 xv = *reinterpret_cast<const float4*>(&xs[px][k * 4]);
            const float4 wa = *reinterpret_cast<const float4*>(&ws1[oc][k * 4]);
            const float4 wb = *reinterpret_cast<const float4*>(&ws2[oc][k * 4]);
            const f32x2 xl = {xv.x, xv.y}, xh = {xv.z, xv.w};
            a1l += xl * (f32x2){wa.x, wa.y};
            a1h += xh * (f32x2){wa.z, wa.w};
            a2l += xl * (f32x2){wb.x, wb.y};
            a2h += xh * (f32x2){wb.z, wb.w};
        }
        const float acc1 = a1l.x + a1l.y + a1h.x + a1h.y;
        const float acc2 = a2l.x + a2l.y + a2h.x + a2h.y;
        v1out = silu(acc1 * s1[oc] + b1[oc]);
        v2out = silu(acc2 * s2[oc] + b2[oc]);
        aT[px][oc] = v1out;              // LDS only before the barrier
    }
    __syncthreads();                     // drains lgkm only (no global stores)

    // ---- phase 3: m1 (f32x2), thread = (px, oc16), first 256 threads ----
    float ymout = 0.f;
    if (t < 256) {
        const int oc16 = t >> 4;
        f32x2 A = {0.f, 0.f};
        #pragma unroll
        for (int k = 0; k < 16; ++k) {
            const f32x2 av = *reinterpret_cast<const f32x2*>(&aT[px][k * 2]);
            const f32x2 wv2 = *reinterpret_cast<const f32x2*>(&wsm1[oc16][k * 2]);
            A += av * wv2;
        }
        ymout = silu((A.x + A.y) * sm1[oc16] + bm1[oc16]);
    }

    // ---- deferred global stores (drain at kernel end, not at a barrier) ----
    {
        const int hw2 = hw0 + px;
        a[((size_t)(bb * 32 + oc)) * HW + hw2]    = v1out;
        bbuf[((size_t)(bb * 32 + oc)) * HW + hw2] = v2out;
        if (t < 256)
            y16[((size_t)(bb * 16 + (t >> 4))) * HW + hw2] = ymout;
    }
}

// ---------------------------------------------------------------------------
// Kernel 2: m2 (3x3, 16->32, pad 1) + BN + SiLU + residual, then cv3
// (1x1, 64->64). R21 changes:
//  (1) residual `a` loads hoisted to kernel start — the pre-staging barrier
//      drains vmcnt anyway, so their ~200-500 cyc latency hides under the
//      staging loads instead of sitting exposed before the a2 writes.
//  (2) a2 transposed to pixel-major [64][36] (16B-aligned stride): m2 writes
//      its 4 oc as ONE ds_write_b128; cv3 reads 8 ds_read_b128 instead of
//      32 scalar ds_read_b32. LDS 39.9 KB — still 4 blocks/CU.
// ---------------------------------------------------------------------------
__global__ __launch_bounds__(512) void m2cv3_kernel(
    const float* __restrict__ y16, const float* __restrict__ a,
    const float* __restrict__ bbuf,
    const float* __restrict__ wm2, const float* __restrict__ sm2, const float* __restrict__ bm2,
    const float* __restrict__ wc, const float* __restrict__ sc, const float* __restrict__ bc,
    float* __restrict__ out) {
    __shared__ __align__(16) float ys[16][4][88];  // interior at [.][.][4..83]
    __shared__ __align__(16) float a2T[64][36];    // pixel-major, b128-aligned
    __shared__ __align__(16) float bs[32][64];
    const int t = threadIdx.x;
    const int p0 = blockIdx.x * 64;
    const int bi = p0 / HW;
    const int hw0 = p0 - bi * HW;
    const int h0 = hw0 / W;

    const int lane = t & 63;
    const int wv = __builtin_amdgcn_readfirstlane(t >> 6);
    const int hw = hw0 + lane;
    const int oc0 = wv * 4;

    // (1) hoisted residual loads — complete for free at the staging barrier
    float ares[4];
    #pragma unroll
    for (int j = 0; j < 4; ++j)
        ares[j] = a[((size_t)(bi * 32 + oc0 + j)) * HW + hw];

    // halo columns: always outside the image (zero-pad conv) -> zero them
    if (t < 128) {
        const int ch = t >> 3, row = (t >> 1) & 3, side = t & 1;
        ys[ch][row][side ? 84 : 3] = 0.f;
    }
    // interior: 16 ch x 4 rows x 20 float4 (row r = h0-1+row; zero if OOB)
    const float* yb = y16 + (size_t)(bi * 16) * HW;
    for (int e = t; e < 16 * 4 * 20; e += 512) {
        const int ch = e / 80;
        const int rem = e - ch * 80;
        const int row = rem / 20;
        const int k4 = rem - row * 20;
        const int r = h0 - 1 + row;
        float4 v = {0.f, 0.f, 0.f, 0.f};
        if ((unsigned)r < (unsigned)H)
            v = *reinterpret_cast<const float4*>(&yb[(size_t)ch * HW + r * W + k4 * 4]);
        *reinterpret_cast<float4*>(&ys[ch][row][4 + k4 * 4]) = v;
    }
    // bs: 32 ch x 16 float4 (aligned: hw0 is a multiple of 64)
    if (t < 512) {
        const int ic = t >> 4, k4 = t & 15;
        *reinterpret_cast<float4*>(&bs[ic][k4 * 4]) =
            *reinterpret_cast<const float4*>(&bbuf[((size_t)(bi * 32 + ic)) * HW + hw0 + k4 * 4]);
    }
    __syncthreads();

    const int h = hw / W;
    const int w = hw - h * W;
    const int lr = h - h0;

    float acc[4] = {0.f, 0.f, 0.f, 0.f};
    #pragma unroll 2
    for (int ic = 0; ic < 16; ++ic) {
        #pragma unroll
        for (int ky = 0; ky < 3; ++ky) {
            #pragma unroll
            for (int kx = 0; kx < 3; ++kx) {
                const float v = ys[ic][lr + ky][3 + w + kx];
                const int tap = ic * 9 + ky * 3 + kx;
                #pragma unroll
                for (int j = 0; j < 4; ++j)
                    acc[j] += v * wm2[(oc0 + j) * 144 + tap];
            }
        }
    }
    {
        float4 av;
        av.x = ares[0] + silu(acc[0] * sm2[oc0]     + bm2[oc0]);
        av.y = ares[1] + silu(acc[1] * sm2[oc0 + 1] + bm2[oc0 + 1]);
        av.z = ares[2] + silu(acc[2] * sm2[oc0 + 2] + bm2[oc0 + 2]);
        av.w = ares[3] + silu(acc[3] * sm2[oc0 + 3] + bm2[oc0 + 3]);
        *reinterpret_cast<float4*>(&a2T[lane][oc0]) = av;   // one b128 store
    }
    __syncthreads();
    const int oc3 = wv * 8;
    float c_[8] = {0.f, 0.f, 0.f, 0.f, 0.f, 0.f, 0.f, 0.f};
    #pragma unroll
    for (int ic4 = 0; ic4 < 8; ++ic4) {          // a' part: 8 b128 reads
        const float4 av = *reinterpret_cast<const float4*>(&a2T[lane][ic4 * 4]);
        #pragma unroll
        for (int j = 0; j < 8; ++j) {
            const float* wr = &wc[(oc3 + j) * 64 + ic4 * 4];
            c_[j] += av.x * wr[0] + av.y * wr[1] + av.z * wr[2] + av.w * wr[3];
        }
    }
    #pragma unroll 4
    for (int ic = 0; ic < 32; ++ic) {            // b part: scalar (conflict-free)
        const float bv = bs[ic][lane];
        #pragma unroll
        for (int j = 0; j < 8; ++j)
            c_[j] += bv * wc[(oc3 + j) * 64 + 32 + ic];
    }
    #pragma unroll
    for (int j = 0; j < 8; ++j) {
        const int oc = oc3 + j;
        out[((size_t)(bi * 64 + oc)) * HW + hw] = silu(c_[j] * sc[oc] + bc[oc]);
    }
}

// ---------------------------------------------------------------------------
extern "C" void kernel_launch(void* const* d_in, const int* in_sizes, int n_in,
                              void* d_out, int out_size, void* d_ws, size_t ws_size,
                              hipStream_t stream) {
    const float* x    = (const float*)d_in[0];
    const float* cv1w = (const float*)d_in[1];
    const float* cv1s = (const float*)d_in[2];
    const float* cv1b = (const float*)d_in[3];
    const float* cv2w = (const float*)d_in[4];
    const float* cv2s = (const float*)d_in[5];
    const float* cv2b = (const float*)d_in[6];
    const float* m1w  = (const float*)d_in[7];
    const float* m1s  = (const float*)d_in[8];
    const float* m1b  = (const float*)d_in[9];
    const float* m2w  = (const float*)d_in[10];
    const float* m2s  = (const float*)d_in[11];
    const float* m2b  = (const float*)d_in[12];
    const float* cv3w = (const float*)d_in[13];
    const float* cv3s = (const float*)d_in[14];
    const float* cv3b = (const float*)d_in[15];

    float* ws   = (float*)d_ws;
    float* a    = ws;                 // 4*32*6400 = 819200
    float* bbuf = ws + 819200;        // 819200
    float* y16  = ws + 1638400;       // 409600 (end 2048000)

    glcm_stage1_kernel<<<NTILE1, 512, 0, stream>>>(
        x, cv1w, cv1s, cv1b, cv2w, cv2s, cv2b, m1w, m1s, m1b, a, bbuf, y16);
    m2cv3_kernel<<<NTILE2, 512, 0, stream>>>(
        y16, a, bbuf, m2w, m2s, m2b, cv3w, cv3s, cv3b, (float*)d_out);
}